// Round 4
// baseline (996.088 us; speedup 1.0000x reference)
//
#include <hip/hip_runtime.h>
#include <hip/hip_bf16.h>

typedef __attribute__((ext_vector_type(8))) short bfrag8;
typedef __attribute__((ext_vector_type(4))) float f32x4;
typedef __attribute__((ext_vector_type(4))) unsigned int u32x4;

__device__ __forceinline__ unsigned short f2bf(float x) {
  union { float f; unsigned u; } v; v.f = x;
  unsigned r = v.u + 0x7fffu + ((v.u >> 16) & 1u);
  return (unsigned short)(r >> 16);
}
__device__ __forceinline__ unsigned pkbf(float a, float b) {
  return (unsigned)f2bf(a) | ((unsigned)f2bf(b) << 16);
}

// ---------------- prep: convert weights to bf16, precompute gaussian params ----
__global__ void prep_kernel(const float* __restrict__ means, const float* __restrict__ stds,
                            const float* __restrict__ W1, const float* __restrict__ W2,
                            unsigned short* __restrict__ W1bf, unsigned short* __restrict__ W2bf,
                            float* __restrict__ prm /* [3][512]: mean, istd, coef */) {
  int t = blockIdx.x * blockDim.x + threadIdx.x;
  int stride = gridDim.x * blockDim.x;
  for (int i = t; i < 512 * 512; i += stride) W1bf[i] = f2bf(W1[i]);
  for (int i = t; i < 32 * 512; i += stride) W2bf[i] = f2bf(W2[i]);
  for (int i = t; i < 512; i += stride) {
    float s = fabsf(stds[i]) + 0.01f;
    prm[i] = means[i];
    prm[512 + i] = 1.0f / s;
    prm[1024 + i] = 1.0f / (2.5066268f * s);  // 1/(sqrt(2*3.14159)*std)
  }
}

// ---------------- fused main kernel ------------------------------------------
// 512 threads = 8 waves (4M x 2N), 64 flat rows per block.
// g computed straight into A-fragments (registers); only h is staged in LDS.
// hbuf XOR-swizzled: byte = row*1024 + (colbyte ^ ((row&7)<<4))
__global__ __launch_bounds__(512, 4) void fused_kernel(
    const float* __restrict__ rpe, const unsigned short* __restrict__ W1bf,
    const unsigned short* __restrict__ W2bf, const float* __restrict__ prm,
    const float* __restrict__ b1, const float* __restrict__ b2,
    float* __restrict__ out) {
  __shared__ unsigned short hbuf[64 * 512];   // 64 KB (h; later aliased as outbuf)
  __shared__ float rpe_s[64][4];              // 1 KB
  __shared__ float prm_s[3 * 512];            // 6 KB
  __shared__ float b1_s[512];                 // 2 KB

  const int tid = threadIdx.x;
  const int rb = blockIdx.x * 64;             // flat row base

  if (tid < 256) ((float*)rpe_s)[tid] = rpe[rb * 4 + tid];
  for (int i = tid; i < 3 * 512; i += 512) prm_s[i] = prm[i];
  b1_s[tid] = b1[tid];
  __syncthreads();

  const int w = tid >> 6, l = tid & 63;
  const int lr = l & 15, lg = l >> 4;
  const int mw = w >> 1, nw = w & 1;          // 4 M-waves x 2 N-waves
  const int arow = mw * 16 + lr;              // A-row this lane feeds

  const f32x4 xrow = *reinterpret_cast<const f32x4*>(&rpe_s[arow][0]);  // rpe[row][0..3]

  f32x4 zv = {0.f, 0.f, 0.f, 0.f};
  f32x4 acc[16];
#pragma unroll
  for (int nf = 0; nf < 16; ++nf) acc[nf] = zv;

  const unsigned short* Wbase = W1bf + (size_t)(nw * 256 + lr) * 512;

  for (int kb = 0; kb < 16; ++kb) {
    const int k0 = kb * 32 + lg * 8;
    const float x = xrow[k0 >> 7];
    float mn[8], is[8], cf[8];
    *reinterpret_cast<f32x4*>(&mn[0]) = *reinterpret_cast<const f32x4*>(&prm_s[k0]);
    *reinterpret_cast<f32x4*>(&mn[4]) = *reinterpret_cast<const f32x4*>(&prm_s[k0 + 4]);
    *reinterpret_cast<f32x4*>(&is[0]) = *reinterpret_cast<const f32x4*>(&prm_s[512 + k0]);
    *reinterpret_cast<f32x4*>(&is[4]) = *reinterpret_cast<const f32x4*>(&prm_s[512 + k0 + 4]);
    *reinterpret_cast<f32x4*>(&cf[0]) = *reinterpret_cast<const f32x4*>(&prm_s[1024 + k0]);
    *reinterpret_cast<f32x4*>(&cf[4]) = *reinterpret_cast<const f32x4*>(&prm_s[1024 + k0 + 4]);
    unsigned pk[4];
#pragma unroll
    for (int p = 0; p < 4; ++p) {
      float t0 = (x - mn[2 * p]) * is[2 * p];
      float t1 = (x - mn[2 * p + 1]) * is[2 * p + 1];
      float g0 = cf[2 * p] * __expf(-0.5f * t0 * t0);
      float g1 = cf[2 * p + 1] * __expf(-0.5f * t1 * t1);
      pk[p] = pkbf(g0, g1);
    }
    u32x4 pv = {pk[0], pk[1], pk[2], pk[3]};
    bfrag8 a = __builtin_bit_cast(bfrag8, pv);

    const unsigned short* wp = Wbase + k0;
#pragma unroll
    for (int nf = 0; nf < 16; ++nf) {
      bfrag8 b = *reinterpret_cast<const bfrag8*>(wp + (size_t)nf * 16 * 512);
      acc[nf] = __builtin_amdgcn_mfma_f32_16x16x32_bf16(a, b, acc[nf], 0, 0, 0);
    }
  }

  // ---- bias + exact GELU -> hbuf (bf16, swizzled)
#pragma unroll
  for (int nf = 0; nf < 16; ++nf) {
    int col = nw * 256 + nf * 16 + lr;
    float bb = b1_s[col];
#pragma unroll
    for (int bi = 0; bi < 4; ++bi) {
      float v = acc[nf][bi] + bb;
      float hh = 0.5f * v * (1.0f + erff(v * 0.70710678f));
      int row = mw * 16 + lg * 4 + bi;
      int byte = row * 1024 + ((col * 2) ^ ((row & 7) << 4));
      *reinterpret_cast<unsigned short*>((char*)hbuf + byte) = f2bf(hh);
    }
  }
  __syncthreads();

  // ---- GEMM2: out[64][32] = h[64][512] @ W2^T. 8 waves: 4(M) x 2(N).
  const int mf2 = w >> 1, nf2 = w & 1;
  f32x4 acc2 = zv;
  const int row2 = mf2 * 16 + lr;
  for (int kb = 0; kb < 16; ++kb) {
    int cb = (kb * 64 + lg * 16) ^ ((row2 & 7) << 4);
    bfrag8 a = *reinterpret_cast<const bfrag8*>((char*)hbuf + row2 * 1024 + cb);
    bfrag8 b = *reinterpret_cast<const bfrag8*>(W2bf + (size_t)(nf2 * 16 + lr) * 512 + kb * 32 + lg * 8);
    acc2 = __builtin_amdgcn_mfma_f32_16x16x32_bf16(a, b, acc2, 0, 0, 0);
  }
  float b2v = b2[nf2 * 16 + lr];
  __syncthreads();                       // all hbuf reads done -> safe to alias

  float* ob = (float*)hbuf;              // [64][33] padded
#pragma unroll
  for (int bi = 0; bi < 4; ++bi)
    ob[(mf2 * 16 + lg * 4 + bi) * 33 + (nf2 * 16 + lr)] = acc2[bi] + b2v;
  __syncthreads();

  // ---- store transposed: out[b][o][m][n], 64 contiguous n per head
  const int bI = rb >> 16, mI = (rb >> 8) & 255, n0 = rb & 255;
  float* obase = out + ((size_t)(bI * 32) * 256 + mI) * 256 + n0;
#pragma unroll
  for (int p = 0; p < 4; ++p) {
    int e = tid + p * 512;               // 0..2047
    int o = e >> 6, i = e & 63;
    obase[(size_t)o * 65536 + i] = ob[i * 33 + o];
  }
}

// ---------------- launch ------------------------------------------------------
extern "C" void kernel_launch(void* const* d_in, const int* in_sizes, int n_in,
                              void* d_out, int out_size, void* d_ws, size_t ws_size,
                              hipStream_t stream) {
  const float* rpe   = (const float*)d_in[0];
  const float* means = (const float*)d_in[1];
  const float* stds  = (const float*)d_in[2];
  const float* W1    = (const float*)d_in[3];
  const float* b1    = (const float*)d_in[4];
  const float* W2    = (const float*)d_in[5];
  const float* b2    = (const float*)d_in[6];
  float* out = (float*)d_out;

  char* ws = (char*)d_ws;
  unsigned short* W1bf = (unsigned short*)ws;             // 512*512*2 = 524288 B
  unsigned short* W2bf = (unsigned short*)(ws + 524288);  // 32*512*2  =  32768 B
  float* prm = (float*)(ws + 557056);                     // 3*512*4   =   6144 B

  prep_kernel<<<256, 256, 0, stream>>>(means, stds, W1, W2, W1bf, W2bf, prm);
  fused_kernel<<<4096, 512, 0, stream>>>(rpe, W1bf, W2bf, prm, b1, b2, out);
}

// Round 5
// 352.068 us; speedup vs baseline: 2.8293x; 2.8293x over previous
//
#include <hip/hip_runtime.h>
#include <hip/hip_bf16.h>

typedef __attribute__((ext_vector_type(8))) short bfrag8;
typedef __attribute__((ext_vector_type(4))) float f32x4;
typedef __attribute__((ext_vector_type(4))) unsigned int u32x4;

__device__ __forceinline__ unsigned short f2bf(float x) {
  union { float f; unsigned u; } v; v.f = x;
  unsigned r = v.u + 0x7fffu + ((v.u >> 16) & 1u);
  return (unsigned short)(r >> 16);
}
__device__ __forceinline__ unsigned pkbf(float a, float b) {
  return (unsigned)f2bf(a) | ((unsigned)f2bf(b) << 16);
}

// ---------------- prep: convert weights to bf16, precompute gaussian params ----
__global__ void prep_kernel(const float* __restrict__ means, const float* __restrict__ stds,
                            const float* __restrict__ W1, const float* __restrict__ W2,
                            unsigned short* __restrict__ W1bf, unsigned short* __restrict__ W2bf,
                            float* __restrict__ prm /* [3][512]: mean, istd, coef */) {
  int t = blockIdx.x * blockDim.x + threadIdx.x;
  int stride = gridDim.x * blockDim.x;
  for (int i = t; i < 512 * 512; i += stride) W1bf[i] = f2bf(W1[i]);
  for (int i = t; i < 32 * 512; i += stride) W2bf[i] = f2bf(W2[i]);
  for (int i = t; i < 512; i += stride) {
    float s = fabsf(stds[i]) + 0.01f;
    prm[i] = means[i];
    prm[512 + i] = 1.0f / s;
    prm[1024 + i] = 1.0f / (2.5066268f * s);  // 1/(sqrt(2*3.14159)*std)
  }
}

// ---------------- fused main kernel ------------------------------------------
// 512 threads = 8 waves (2M x 4N), 64 flat rows per block.
// A (gaussian g) computed in registers; B (W1 k-slice, 32KB) double-buffered in
// LDS via global_load_lds. LDS B layout: frag(j,lg) at (j>>4)*1024 + lg*256 +
// (j&15)*16  -> every wave ds_read_b128 is a contiguous 1KB (conflict-free).
__global__ __launch_bounds__(512, 4) void fused_kernel(
    const float* __restrict__ rpe, const unsigned short* __restrict__ W1bf,
    const unsigned short* __restrict__ W2bf, const float* __restrict__ prm,
    const float* __restrict__ b1, const float* __restrict__ b2,
    float* __restrict__ out) {
  __shared__ __attribute__((aligned(16))) char lds[64 * 1024 + 6 * 1024 + 1024];
  // [0,64K): B double-buffer (2x32KB), later h[64][512] bf16, later out[64][33] f32
  // [64K, 64K+6K): prm_s   [70K, 71K): rpe_s[64][4]
  float* prm_s = (float*)(lds + 65536);
  float* rpe_s = (float*)(lds + 65536 + 6144);

  const int tid = threadIdx.x;
  const int rb = blockIdx.x * 64;

  if (tid < 256) rpe_s[tid] = rpe[rb * 4 + tid];
  for (int i = tid; i < 1536; i += 512) prm_s[i] = prm[i];

  // staging chunk map: c = i*512 + tid; j = (c>>6)*16 + (c&15); lg = (c>>4)&3
  // global elems: j*512 + lg*8 (+kb*32); lds byte: buf*32768 + i*8192 + tid*16
  int goff[4];
#pragma unroll
  for (int i = 0; i < 4; ++i) {
    int c = i * 512 + tid;
    int j = ((c >> 6) << 4) + (c & 15);
    goff[i] = j * 512 + ((c >> 4) & 3) * 8;
  }
  const char* Wc = (const char*)W1bf;

#define STAGE(buf, kb)                                                          \
  {                                                                             \
    _Pragma("unroll") for (int i_ = 0; i_ < 4; ++i_) {                          \
      const void* gp = (const void*)(Wc + (size_t)goff[i_] * 2 + (kb) * 64);    \
      void* lp = (void*)(lds + (buf) * 32768 + i_ * 8192 + tid * 16);           \
      __builtin_amdgcn_global_load_lds(                                         \
          (const __attribute__((address_space(1))) void*)gp,                    \
          (__attribute__((address_space(3))) void*)lp, 16, 0, 0);               \
    }                                                                           \
  }

  STAGE(0, 0);
  __syncthreads();   // rpe/prm + B slice 0 ready

  const int w = tid >> 6, l = tid & 63;
  const int lr = l & 15, lg = l >> 4;
  const int mw = w >> 2, nw = w & 3;     // 2 M-waves x 4 N-waves
  const int r0 = mw * 32 + lr;           // A row (mf=0); mf=1 -> +16

  f32x4 zv = {0.f, 0.f, 0.f, 0.f};
  f32x4 acc[2][8];
#pragma unroll
  for (int mf = 0; mf < 2; ++mf)
#pragma unroll
    for (int nf = 0; nf < 8; ++nf) acc[mf][nf] = zv;

  const f32x4* prm4 = (const f32x4*)prm_s;
  int cur = 0;

#pragma unroll
  for (int kb = 0; kb < 16; ++kb) {
    if (kb < 15) STAGE(cur ^ 1, kb + 1);

    // ---- A fragments (2 rows per lane), 16 exps
    const int k0 = kb * 32 + lg * 8;
    const float x0 = rpe_s[r0 * 4 + (kb >> 2)];
    const float x1 = rpe_s[(r0 + 16) * 4 + (kb >> 2)];
    unsigned pk0[4], pk1[4];
#pragma unroll
    for (int hh = 0; hh < 2; ++hh) {
      f32x4 M = prm4[(k0 >> 2) + hh];
      f32x4 I = prm4[128 + (k0 >> 2) + hh];
      f32x4 C = prm4[256 + (k0 >> 2) + hh];
#pragma unroll
      for (int p = 0; p < 2; ++p) {
        float m0 = M[2 * p], m1 = M[2 * p + 1];
        float i0 = I[2 * p], i1 = I[2 * p + 1];
        float c0 = C[2 * p], c1 = C[2 * p + 1];
        float t00 = (x0 - m0) * i0, t01 = (x0 - m1) * i1;
        float t10 = (x1 - m0) * i0, t11 = (x1 - m1) * i1;
        pk0[hh * 2 + p] = pkbf(c0 * __expf(-0.5f * t00 * t00), c1 * __expf(-0.5f * t01 * t01));
        pk1[hh * 2 + p] = pkbf(c0 * __expf(-0.5f * t10 * t10), c1 * __expf(-0.5f * t11 * t11));
      }
    }
    u32x4 av0 = {pk0[0], pk0[1], pk0[2], pk0[3]};
    u32x4 av1 = {pk1[0], pk1[1], pk1[2], pk1[3]};
    bfrag8 a0 = __builtin_bit_cast(bfrag8, av0);
    bfrag8 a1 = __builtin_bit_cast(bfrag8, av1);

    // ---- B fragments from LDS (contiguous per wave) + MFMA
    const char* Bbase = lds + cur * 32768 + (nw * 8) * 1024 + lg * 256 + lr * 16;
#pragma unroll
    for (int nf = 0; nf < 8; ++nf) {
      bfrag8 b = *(const bfrag8*)(Bbase + nf * 1024);
      acc[0][nf] = __builtin_amdgcn_mfma_f32_16x16x32_bf16(a0, b, acc[0][nf], 0, 0, 0);
      acc[1][nf] = __builtin_amdgcn_mfma_f32_16x16x32_bf16(a1, b, acc[1][nf], 0, 0, 0);
    }
    __syncthreads();
    cur ^= 1;
  }

  // ---- bias + exact GELU -> h in LDS [64][512] bf16, XOR-swizzled rows
  unsigned short* hbuf = (unsigned short*)lds;
#pragma unroll
  for (int nf = 0; nf < 8; ++nf) {
    int col = nw * 128 + nf * 16 + lr;
    float bb = b1[col];
#pragma unroll
    for (int mf = 0; mf < 2; ++mf) {
#pragma unroll
      for (int bi = 0; bi < 4; ++bi) {
        float v = acc[mf][nf][bi] + bb;
        float g = 0.5f * v * (1.0f + erff(v * 0.70710678f));
        int row = mw * 32 + mf * 16 + lg * 4 + bi;
        int byte = row * 1024 + ((col * 2) ^ ((row & 7) << 4));
        *(unsigned short*)((char*)hbuf + byte) = f2bf(g);
      }
    }
  }
  __syncthreads();

  // ---- GEMM2: out[64][32] = h @ W2^T. 8 waves: 4(M) x 2(N).
  const int mf2 = w >> 1, nf2 = w & 1;
  f32x4 acc2 = zv;
  const int row2 = mf2 * 16 + lr;
  for (int kb = 0; kb < 16; ++kb) {
    int cb = (kb * 64 + lg * 16) ^ ((row2 & 7) << 4);
    bfrag8 a = *(const bfrag8*)((char*)hbuf + row2 * 1024 + cb);
    bfrag8 b = *(const bfrag8*)(W2bf + (size_t)(nf2 * 16 + lr) * 512 + kb * 32 + lg * 8);
    acc2 = __builtin_amdgcn_mfma_f32_16x16x32_bf16(a, b, acc2, 0, 0, 0);
  }
  float b2v = b2[nf2 * 16 + lr];
  __syncthreads();                     // all h reads done -> safe to overlay

  float* ob = (float*)lds;             // [64][33] padded
#pragma unroll
  for (int bi = 0; bi < 4; ++bi)
    ob[(mf2 * 16 + lg * 4 + bi) * 33 + (nf2 * 16 + lr)] = acc2[bi] + b2v;
  __syncthreads();

  // ---- store transposed: out[b][o][m][n], 64 contiguous n per head
  const int bI = rb >> 16, mI = (rb >> 8) & 255, n0 = rb & 255;
  float* obase = out + ((size_t)(bI * 32) * 256 + mI) * 256 + n0;
#pragma unroll
  for (int p = 0; p < 4; ++p) {
    int e = tid + p * 512;             // 0..2047
    int o = e >> 6, i = e & 63;
    obase[(size_t)o * 65536 + i] = ob[i * 33 + o];
  }
#undef STAGE
}

// ---------------- launch ------------------------------------------------------
extern "C" void kernel_launch(void* const* d_in, const int* in_sizes, int n_in,
                              void* d_out, int out_size, void* d_ws, size_t ws_size,
                              hipStream_t stream) {
  const float* rpe   = (const float*)d_in[0];
  const float* means = (const float*)d_in[1];
  const float* stds  = (const float*)d_in[2];
  const float* W1    = (const float*)d_in[3];
  const float* b1    = (const float*)d_in[4];
  const float* W2    = (const float*)d_in[5];
  const float* b2    = (const float*)d_in[6];
  float* out = (float*)d_out;

  char* ws = (char*)d_ws;
  unsigned short* W1bf = (unsigned short*)ws;             // 512*512*2 = 524288 B
  unsigned short* W2bf = (unsigned short*)(ws + 524288);  // 32*512*2  =  32768 B
  float* prm = (float*)(ws + 557056);                     // 3*512*4   =   6144 B

  prep_kernel<<<256, 256, 0, stream>>>(means, stds, W1, W2, W1bf, W2bf, prm);
  fused_kernel<<<4096, 512, 0, stream>>>(rpe, W1bf, W2bf, prm, b1, b2, out);
}

// Round 6
// 346.331 us; speedup vs baseline: 2.8761x; 1.0166x over previous
//
#include <hip/hip_runtime.h>
#include <hip/hip_bf16.h>

typedef __attribute__((ext_vector_type(8))) short bfrag8;
typedef __attribute__((ext_vector_type(4))) float f32x4;
typedef __attribute__((ext_vector_type(4))) unsigned int u32x4;

#if __has_builtin(__builtin_amdgcn_exp2f)
#define GEXP(x) __builtin_amdgcn_exp2f(x)
#define IS2_SCALE 0.84932180028801907f   /* sqrt(0.5*log2(e)) : exp2(-(t*s)^2)=exp(-t^2/2) */
#else
#define GEXP(x) __expf(x)
#define IS2_SCALE 0.70710678118654752f   /* sqrt(0.5) */
#endif

__device__ __forceinline__ unsigned short f2bf(float x) {
  union { float f; unsigned u; } v; v.f = x;
  unsigned r = v.u + 0x7fffu + ((v.u >> 16) & 1u);
  return (unsigned short)(r >> 16);
}
__device__ __forceinline__ unsigned cvtpk(float lo, float hi) {
  unsigned r;
  asm("v_cvt_pk_bf16_f32 %0, %1, %2" : "=v"(r) : "v"(lo), "v"(hi));
  return r;
}

// ---------------- prep: weights->bf16, folded gaussian params -----------------
__global__ void prep_kernel(const float* __restrict__ means, const float* __restrict__ stds,
                            const float* __restrict__ W1, const float* __restrict__ W2,
                            unsigned short* __restrict__ W1bf, unsigned short* __restrict__ W2bf,
                            float* __restrict__ prm /* [3][512]: mis2, is2, coef */) {
  int t = blockIdx.x * blockDim.x + threadIdx.x;
  int stride = gridDim.x * blockDim.x;
  for (int i = t; i < 512 * 512; i += stride) W1bf[i] = f2bf(W1[i]);
  for (int i = t; i < 32 * 512; i += stride) W2bf[i] = f2bf(W2[i]);
  for (int i = t; i < 512; i += stride) {
    float s = fabsf(stds[i]) + 0.01f;
    float is2 = (1.0f / s) * IS2_SCALE;
    prm[i] = -means[i] * is2;            // mis2
    prm[512 + i] = is2;                  // is2
    prm[1024 + i] = 1.0f / (2.5066268f * s);  // 1/(sqrt(2*3.14159)*std)
  }
}

// ---------------- fused main kernel ------------------------------------------
// 512 threads = 8 waves (4M x 2N), 64 flat rows per block.
// A (gaussian g) computed in registers (1 row/lane, 2x dup); B (W1 k-slice,
// 32KB) double-buffered in LDS via global_load_lds. LDS B layout: frag(j,lg)
// at (j>>4)*1024 + lg*256 + (j&15)*16 -> wave ds_read_b128 = contiguous 1KB.
__global__ __launch_bounds__(512, 4) void fused_kernel(
    const float* __restrict__ rpe, const unsigned short* __restrict__ W1bf,
    const unsigned short* __restrict__ W2bf, const float* __restrict__ prm,
    const float* __restrict__ b1, const float* __restrict__ b2,
    float* __restrict__ out) {
  __shared__ __attribute__((aligned(16))) char lds[64 * 1024 + 6 * 1024 + 1024];
  // [0,64K): B dbuf (2x32KB) -> h[64][512] bf16 -> out[64][33] f32
  float* prm_s = (float*)(lds + 65536);
  float* rpe_s = (float*)(lds + 65536 + 6144);

  const int tid = threadIdx.x;
  const int rb = blockIdx.x * 64;

  if (tid < 256) rpe_s[tid] = rpe[rb * 4 + tid];
  for (int i = tid; i < 1536; i += 512) prm_s[i] = prm[i];

  int goff[4];
#pragma unroll
  for (int i = 0; i < 4; ++i) {
    int c = i * 512 + tid;
    int j = ((c >> 6) << 4) + (c & 15);
    goff[i] = j * 512 + ((c >> 4) & 3) * 8;
  }
  const char* Wc = (const char*)W1bf;

#define STAGE(buf, kb)                                                          \
  {                                                                             \
    _Pragma("unroll") for (int i_ = 0; i_ < 4; ++i_) {                          \
      const void* gp = (const void*)(Wc + (size_t)goff[i_] * 2 + (kb) * 64);    \
      void* lp = (void*)(lds + (buf) * 32768 + i_ * 8192 + tid * 16);           \
      __builtin_amdgcn_global_load_lds(                                         \
          (const __attribute__((address_space(1))) void*)gp,                    \
          (__attribute__((address_space(3))) void*)lp, 16, 0, 0);               \
    }                                                                           \
  }

  STAGE(0, 0);
  __syncthreads();   // rpe/prm + B slice 0 ready

  const int w = tid >> 6, l = tid & 63;
  const int lr = l & 15, lg = l >> 4;
  const int mw = w >> 1, nw = w & 1;     // 4 M-waves x 2 N-waves
  const int row = mw * 16 + lr;          // this lane's A row

  f32x4 zv = {0.f, 0.f, 0.f, 0.f};
  f32x4 acc[16];
#pragma unroll
  for (int nf = 0; nf < 16; ++nf) acc[nf] = zv;

  const f32x4* prm4 = (const f32x4*)prm_s;
  int cur = 0;

#pragma unroll
  for (int kb = 0; kb < 16; ++kb) {
    if (kb < 15) STAGE(cur ^ 1, kb + 1);

    // ---- A fragment: 8 gaussians for (row, k0..k0+7)
    const int k0 = kb * 32 + lg * 8;
    const float x = rpe_s[row * 4 + (kb >> 2)];
    unsigned pk[4];
#pragma unroll
    for (int hh = 0; hh < 2; ++hh) {
      f32x4 M = prm4[(k0 >> 2) + hh];          // mis2
      f32x4 I = prm4[128 + (k0 >> 2) + hh];    // is2
      f32x4 C = prm4[256 + (k0 >> 2) + hh];    // coef
#pragma unroll
      for (int p = 0; p < 2; ++p) {
        float u0 = __builtin_fmaf(x, I[2 * p], M[2 * p]);
        float u1 = __builtin_fmaf(x, I[2 * p + 1], M[2 * p + 1]);
        float g0 = C[2 * p] * GEXP(-u0 * u0);
        float g1 = C[2 * p + 1] * GEXP(-u1 * u1);
        pk[hh * 2 + p] = cvtpk(g0, g1);
      }
    }
    u32x4 av = {pk[0], pk[1], pk[2], pk[3]};
    bfrag8 a = __builtin_bit_cast(bfrag8, av);

    // ---- B fragments from LDS (contiguous per wave) + MFMA
    const char* Bbase = lds + cur * 32768 + nw * 16384 + lg * 256 + lr * 16;
#pragma unroll
    for (int nf = 0; nf < 16; ++nf) {
      bfrag8 b = *(const bfrag8*)(Bbase + nf * 1024);
      acc[nf] = __builtin_amdgcn_mfma_f32_16x16x32_bf16(a, b, acc[nf], 0, 0, 0);
    }
    __syncthreads();
    cur ^= 1;
  }

  // ---- bias + exact GELU -> h in LDS [64][512] bf16, XOR-swizzled rows
  unsigned short* hbuf = (unsigned short*)lds;
#pragma unroll
  for (int nf = 0; nf < 16; ++nf) {
    int col = nw * 256 + nf * 16 + lr;
    float bb = b1[col];
#pragma unroll
    for (int bi = 0; bi < 4; ++bi) {
      float v = acc[nf][bi] + bb;
      float g = 0.5f * v * (1.0f + erff(v * 0.70710678f));
      int hrow = mw * 16 + lg * 4 + bi;
      int byte = hrow * 1024 + ((col * 2) ^ ((hrow & 7) << 4));
      *(unsigned short*)((char*)hbuf + byte) = f2bf(g);
    }
  }
  __syncthreads();

  // ---- GEMM2: out[64][32] = h @ W2^T. 8 waves: 4(M) x 2(N).
  const int mf2 = w >> 1, nf2 = w & 1;
  f32x4 acc2 = zv;
  const int row2 = mf2 * 16 + lr;
  for (int kb = 0; kb < 16; ++kb) {
    int cb = (kb * 64 + lg * 16) ^ ((row2 & 7) << 4);
    bfrag8 a = *(const bfrag8*)((char*)hbuf + row2 * 1024 + cb);
    bfrag8 b = *(const bfrag8*)(W2bf + (size_t)(nf2 * 16 + lr) * 512 + kb * 32 + lg * 8);
    acc2 = __builtin_amdgcn_mfma_f32_16x16x32_bf16(a, b, acc2, 0, 0, 0);
  }
  float b2v = b2[nf2 * 16 + lr];
  __syncthreads();                     // all h reads done -> safe to overlay

  float* ob = (float*)lds;             // [64][33] padded
#pragma unroll
  for (int bi = 0; bi < 4; ++bi)
    ob[(mf2 * 16 + lg * 4 + bi) * 33 + (nf2 * 16 + lr)] = acc2[bi] + b2v;
  __syncthreads();

  // ---- store transposed: out[b][o][m][n], 64 contiguous n per head
  const int bI = rb >> 16, mI = (rb >> 8) & 255, n0 = rb & 255;
  float* obase = out + ((size_t)(bI * 32) * 256 + mI) * 256 + n0;
#pragma unroll
  for (int p = 0; p < 4; ++p) {
    int e = tid + p * 512;             // 0..2047
    int o = e >> 6, i = e & 63;
    obase[(size_t)o * 65536 + i] = ob[i * 33 + o];
  }
#undef STAGE
}

// ---------------- launch ------------------------------------------------------
extern "C" void kernel_launch(void* const* d_in, const int* in_sizes, int n_in,
                              void* d_out, int out_size, void* d_ws, size_t ws_size,
                              hipStream_t stream) {
  const float* rpe   = (const float*)d_in[0];
  const float* means = (const float*)d_in[1];
  const float* stds  = (const float*)d_in[2];
  const float* W1    = (const float*)d_in[3];
  const float* b1    = (const float*)d_in[4];
  const float* W2    = (const float*)d_in[5];
  const float* b2    = (const float*)d_in[6];
  float* out = (float*)d_out;

  char* ws = (char*)d_ws;
  unsigned short* W1bf = (unsigned short*)ws;             // 512*512*2 = 524288 B
  unsigned short* W2bf = (unsigned short*)(ws + 524288);  // 32*512*2  =  32768 B
  float* prm = (float*)(ws + 557056);                     // 3*512*4   =   6144 B

  prep_kernel<<<256, 256, 0, stream>>>(means, stds, W1, W2, W1bf, W2bf, prm);
  fused_kernel<<<4096, 512, 0, stream>>>(rpe, W1bf, W2bf, prm, b1, b2, out);
}

// Round 8
// 305.742 us; speedup vs baseline: 3.2579x; 1.1328x over previous
//
#include <hip/hip_runtime.h>
#include <hip/hip_bf16.h>

typedef __attribute__((ext_vector_type(8))) short bfrag8;
typedef __attribute__((ext_vector_type(4))) float f32x4;
typedef __attribute__((ext_vector_type(4))) unsigned int u32x4;

#if __has_builtin(__builtin_amdgcn_exp2f)
#define GEXP(x) __builtin_amdgcn_exp2f(x)
#define IS2_SCALE 0.84932180028801907f   /* sqrt(0.5*log2(e)) : exp2(-(t*s)^2)=exp(-t^2/2) */
#else
#define GEXP(x) __expf(x)
#define IS2_SCALE 0.70710678118654752f   /* sqrt(0.5) */
#endif

__device__ __forceinline__ unsigned short f2bf(float x) {
  union { float f; unsigned u; } v; v.f = x;
  unsigned r = v.u + 0x7fffu + ((v.u >> 16) & 1u);
  return (unsigned short)(r >> 16);
}
__device__ __forceinline__ unsigned cvtpk(float lo, float hi) {
  unsigned r;
  asm("v_cvt_pk_bf16_f32 %0, %1, %2" : "=v"(r) : "v"(lo), "v"(hi));
  return r;
}

// ---------------- prep: weights->bf16, folded gaussian params -----------------
__global__ void prep_kernel(const float* __restrict__ means, const float* __restrict__ stds,
                            const float* __restrict__ W1, const float* __restrict__ W2,
                            unsigned short* __restrict__ W1bf, unsigned short* __restrict__ W2bf,
                            float* __restrict__ prm /* [3][512]: mis2, is2, coef */) {
  int t = blockIdx.x * blockDim.x + threadIdx.x;
  int stride = gridDim.x * blockDim.x;
  for (int i = t; i < 512 * 512; i += stride) W1bf[i] = f2bf(W1[i]);
  for (int i = t; i < 32 * 512; i += stride) W2bf[i] = f2bf(W2[i]);
  for (int i = t; i < 512; i += stride) {
    float s = fabsf(stds[i]) + 0.01f;
    float is2 = (1.0f / s) * IS2_SCALE;
    prm[i] = -means[i] * is2;            // mis2
    prm[512 + i] = is2;                  // is2
    prm[1024 + i] = 1.0f / (2.5066268f * s);  // 1/(sqrt(2*3.14159)*std)
  }
}

// ---------------- fused main kernel ------------------------------------------
// 512 threads = 8 waves (4M x 2N), 64 flat rows per block.
// A (gaussian g) in registers; B (W1 32KB k-slice) double-buffered in LDS via
// global_load_lds. Per-iter: counted vmcnt BEFORE barrier1 (collective staging
// complete), MFMA cluster, barrier2 (reads done before buffer reuse). The
// just-issued stage stays in flight across both barriers (T3/T4).
__global__ __launch_bounds__(512, 4) void fused_kernel(
    const float* __restrict__ rpe, const unsigned short* __restrict__ W1bf,
    const unsigned short* __restrict__ W2bf, const float* __restrict__ prm,
    const float* __restrict__ b1, const float* __restrict__ b2,
    float* __restrict__ out) {
  __shared__ __attribute__((aligned(16))) char lds[65536 + 6144 + 1024 + 2048];
  // [0,64K): B dbuf (2x32KB) -> h[64][512] bf16 -> out[64][33] f32
  float* prm_s = (float*)(lds + 65536);
  float* rpe_s = (float*)(lds + 65536 + 6144);
  float* b1_s  = (float*)(lds + 65536 + 6144 + 1024);

  const int tid = threadIdx.x;
  const int rb = blockIdx.x * 64;

  if (tid < 256) rpe_s[tid] = rpe[rb * 4 + tid];
  for (int i = tid; i < 1536; i += 512) prm_s[i] = prm[i];
  b1_s[tid] = b1[tid];

  int goff[4];
#pragma unroll
  for (int i = 0; i < 4; ++i) {
    int c = i * 512 + tid;
    int j = ((c >> 6) << 4) + (c & 15);
    goff[i] = j * 512 + ((c >> 4) & 3) * 8;
  }
  const char* Wc = (const char*)W1bf;

#define STAGE(buf, kb)                                                          \
  {                                                                             \
    _Pragma("unroll") for (int i_ = 0; i_ < 4; ++i_) {                          \
      const void* gp = (const void*)(Wc + (size_t)goff[i_] * 2 + (kb) * 64);    \
      void* lp = (void*)(lds + (buf) * 32768 + i_ * 8192 + tid * 16);           \
      __builtin_amdgcn_global_load_lds(                                         \
          (const __attribute__((address_space(1))) void*)gp,                    \
          (__attribute__((address_space(3))) void*)lp, 16, 0, 0);               \
    }                                                                           \
  }

  STAGE(0, 0);
  __syncthreads();   // full drain: rpe/prm/b1 + B slice 0 collectively ready

  const int w = tid >> 6, l = tid & 63;
  const int lr = l & 15, lg = l >> 4;
  const int mw = w >> 1, nw = w & 1;     // 4 M-waves x 2 N-waves
  const int row = mw * 16 + lr;          // this lane's A row

  f32x4 zv = {0.f, 0.f, 0.f, 0.f};
  f32x4 acc[16];
#pragma unroll
  for (int nf = 0; nf < 16; ++nf) acc[nf] = zv;

  const f32x4* prm4 = (const f32x4*)prm_s;
  int cur = 0;

#pragma unroll
  for (int kb = 0; kb < 16; ++kb) {
    if (kb < 15) STAGE(cur ^ 1, kb + 1);

    // ---- A fragment: 8 gaussians for (row, k0..k0+7) — independent of stage
    const int k0 = kb * 32 + lg * 8;
    const float x = rpe_s[row * 4 + (kb >> 2)];
    unsigned pk[4];
#pragma unroll
    for (int hh = 0; hh < 2; ++hh) {
      f32x4 M = prm4[(k0 >> 2) + hh];          // mis2
      f32x4 I = prm4[128 + (k0 >> 2) + hh];    // is2
      f32x4 C = prm4[256 + (k0 >> 2) + hh];    // coef
#pragma unroll
      for (int p = 0; p < 2; ++p) {
        float u0 = __builtin_fmaf(x, I[2 * p], M[2 * p]);
        float u1 = __builtin_fmaf(x, I[2 * p + 1], M[2 * p + 1]);
        float g0 = C[2 * p] * GEXP(-u0 * u0);
        float g1 = C[2 * p + 1] * GEXP(-u1 * u1);
        pk[hh * 2 + p] = cvtpk(g0, g1);
      }
    }
    u32x4 av = {pk[0], pk[1], pk[2], pk[3]};
    bfrag8 a = __builtin_bit_cast(bfrag8, av);

    // ---- wait for OWN slice of buffer cur (staged last iter), keep S_kb in
    // flight; then barrier: rendezvous => ALL waves' slices of cur complete.
    if (kb < 15) {
      asm volatile("s_waitcnt vmcnt(4)" ::: "memory");
    } else {
      asm volatile("s_waitcnt vmcnt(0)" ::: "memory");
    }
    __builtin_amdgcn_s_barrier();            // barrier 1: cur fully staged
    __builtin_amdgcn_sched_barrier(0);

    // ---- B fragments from LDS (contiguous per wave) + MFMA
    const char* Bbase = lds + cur * 32768 + nw * 16384 + lg * 256 + lr * 16;
    __builtin_amdgcn_s_setprio(1);
#pragma unroll
    for (int nf = 0; nf < 16; ++nf) {
      bfrag8 b = *(const bfrag8*)(Bbase + nf * 1024);
      acc[nf] = __builtin_amdgcn_mfma_f32_16x16x32_bf16(a, b, acc[nf], 0, 0, 0);
    }
    __builtin_amdgcn_s_setprio(0);

    __builtin_amdgcn_s_barrier();            // barrier 2: cur reads done
    cur ^= 1;
  }

  // ---- bias + exact GELU -> h in LDS [64][512] bf16, XOR-swizzled rows
  unsigned short* hbuf = (unsigned short*)lds;
#pragma unroll
  for (int nf = 0; nf < 16; ++nf) {
    int col = nw * 256 + nf * 16 + lr;
    float bb = b1_s[col];
#pragma unroll
    for (int bi = 0; bi < 4; ++bi) {
      float v = acc[nf][bi] + bb;
      float g = 0.5f * v * (1.0f + erff(v * 0.70710678f));
      int hrow = mw * 16 + lg * 4 + bi;
      int byte = hrow * 1024 + ((col * 2) ^ ((hrow & 7) << 4));
      *(unsigned short*)((char*)hbuf + byte) = f2bf(g);
    }
  }
  __syncthreads();

  // ---- GEMM2: out[64][32] = h @ W2^T. 8 waves: 4(M) x 2(N).
  const int mf2 = w >> 1, nf2 = w & 1;
  f32x4 acc2 = zv;
  const int row2 = mf2 * 16 + lr;
  for (int kb = 0; kb < 16; ++kb) {
    int cb = (kb * 64 + lg * 16) ^ ((row2 & 7) << 4);
    bfrag8 a = *(const bfrag8*)((char*)hbuf + row2 * 1024 + cb);
    bfrag8 b = *(const bfrag8*)(W2bf + (size_t)(nf2 * 16 + lr) * 512 + kb * 32 + lg * 8);
    acc2 = __builtin_amdgcn_mfma_f32_16x16x32_bf16(a, b, acc2, 0, 0, 0);
  }
  float b2v = b2[nf2 * 16 + lr];
  __syncthreads();                     // all h reads done -> safe to overlay

  float* ob = (float*)lds;             // [64][33] padded
#pragma unroll
  for (int bi = 0; bi < 4; ++bi)
    ob[(mf2 * 16 + lg * 4 + bi) * 33 + (nf2 * 16 + lr)] = acc2[bi] + b2v;
  __syncthreads();

  // ---- store transposed: out[b][o][m][n], 64 contiguous n per head
  const int bI = rb >> 16, mI = (rb >> 8) & 255, n0 = rb & 255;
  float* obase = out + ((size_t)(bI * 32) * 256 + mI) * 256 + n0;
#pragma unroll
  for (int p = 0; p < 4; ++p) {
    int e = tid + p * 512;             // 0..2047
    int o = e >> 6, i = e & 63;
    obase[(size_t)o * 65536 + i] = ob[i * 33 + o];
  }
#undef STAGE
}

// ---------------- launch ------------------------------------------------------
extern "C" void kernel_launch(void* const* d_in, const int* in_sizes, int n_in,
                              void* d_out, int out_size, void* d_ws, size_t ws_size,
                              hipStream_t stream) {
  const float* rpe   = (const float*)d_in[0];
  const float* means = (const float*)d_in[1];
  const float* stds  = (const float*)d_in[2];
  const float* W1    = (const float*)d_in[3];
  const float* b1    = (const float*)d_in[4];
  const float* W2    = (const float*)d_in[5];
  const float* b2    = (const float*)d_in[6];
  float* out = (float*)d_out;

  char* ws = (char*)d_ws;
  unsigned short* W1bf = (unsigned short*)ws;             // 512*512*2 = 524288 B
  unsigned short* W2bf = (unsigned short*)(ws + 524288);  // 32*512*2  =  32768 B
  float* prm = (float*)(ws + 557056);                     // 3*512*4   =   6144 B

  prep_kernel<<<256, 256, 0, stream>>>(means, stds, W1, W2, W1bf, W2bf, prm);
  fused_kernel<<<4096, 512, 0, stream>>>(rpe, W1bf, W2bf, prm, b1, b2, out);
}